// Round 1
// baseline (813.582 us; speedup 1.0000x reference)
//
#include <hip/hip_runtime.h>

#define VOXEL 0.0625f

// ---------------- pose kernel ----------------
__device__ void inv4(const float* a_in, float* out) {
  float a[4][8];
  for (int i = 0; i < 4; i++) {
    for (int j = 0; j < 4; j++) { a[i][j] = a_in[i*4+j]; a[i][j+4] = (i==j) ? 1.f : 0.f; }
  }
  for (int col = 0; col < 4; col++) {
    int piv = col; float mx = fabsf(a[col][col]);
    for (int r = col+1; r < 4; r++) { float v = fabsf(a[r][col]); if (v > mx) { mx = v; piv = r; } }
    if (piv != col) for (int j = 0; j < 8; j++) { float t = a[col][j]; a[col][j] = a[piv][j]; a[piv][j] = t; }
    float d = 1.f / a[col][col];
    for (int j = 0; j < 8; j++) a[col][j] *= d;
    for (int r = 0; r < 4; r++) if (r != col) {
      float f = a[r][col];
      for (int j = 0; j < 8; j++) a[r][j] -= f * a[col][j];
    }
  }
  for (int i = 0; i < 4; i++) for (int j = 0; j < 4; j++) out[i*4+j] = a[i][j+4];
}

// M[b] = top 3 rows of inv(cur @ inv(hist)), matching reference op order
__global__ void pose_kernel(const float* __restrict__ hist, const float* __restrict__ cur,
                            float* __restrict__ M, int B) {
  int b = threadIdx.x;
  if (b >= B) return;
  float Hinv[16], T[16], Tinv[16];
  inv4(hist + b*16, Hinv);
  for (int i = 0; i < 4; i++) for (int j = 0; j < 4; j++) {
    float s = 0.f;
    for (int k = 0; k < 4; k++) s += cur[b*16 + i*4 + k] * Hinv[k*4 + j];
    T[i*4+j] = s;
  }
  inv4(T, Tinv);
  for (int i = 0; i < 3; i++) for (int j = 0; j < 4; j++) M[b*12 + i*4 + j] = Tinv[i*4+j];
}

// ---------------- transpose [B,C,V] -> [B,V,C] ----------------
template<int C>
__global__ __launch_bounds__(256) void transpose_kernel(const float* __restrict__ src,
                                                        float* __restrict__ dst, int V) {
  __shared__ float lds[64*(C+1)];
  int b = blockIdx.y;
  long v0 = (long)blockIdx.x * 64;
  const float* s = src + (long)b * C * V;
  float* d = dst + ((long)b * V + v0) * C;
  int tid = threadIdx.x;
  int vl = tid & 63, cq = tid >> 6;            // 4 channels per pass
  for (int c = cq; c < C; c += 4)
    lds[vl*(C+1) + c] = s[(long)c * V + v0 + vl];
  __syncthreads();
  const int TOT = 64 * C;
  for (int j = tid; j < TOT; j += 256) {
    int v = j / C, c = j & (C - 1);
    d[j] = lds[v*(C+1) + c];
  }
}

// ---------------- sampling ----------------
__device__ inline void make_corners(int D, float res_inv,
                                    float hx, float hy, float hz,
                                    int* voff, float* w) {
  float Dm1 = (float)(D - 1);
  float v0 = hx * res_inv, v1 = hy * res_inv, v2 = hz * res_inv;
  float gx = fminf(fmaxf(v0 / Dm1 * 2.f - 1.f, -1.f), 1.f);
  float gy = fminf(fmaxf(v1 / Dm1 * 2.f - 1.f, -1.f), 1.f);
  float gz = fminf(fmaxf(v2 / Dm1 * 2.f - 1.f, -1.f), 1.f);
  float ix = ((gx + 1.f) * D - 1.f) * 0.5f;   // x indexes W (fastest)
  float iy = ((gy + 1.f) * D - 1.f) * 0.5f;   // y indexes H
  float iz = ((gz + 1.f) * D - 1.f) * 0.5f;   // z indexes D (slowest)
  float fix = floorf(ix), fiy = floorf(iy), fiz = floorf(iz);
  int ix0 = (int)fix, iy0 = (int)fiy, iz0 = (int)fiz;
  float fx = ix - fix, fy = iy - fiy, fz = iz - fiz;
  #pragma unroll
  for (int dz = 0; dz < 2; dz++)
  #pragma unroll
  for (int dy = 0; dy < 2; dy++)
  #pragma unroll
  for (int dx = 0; dx < 2; dx++) {
    int xi = ix0 + dx, yi = iy0 + dy, zi = iz0 + dz;
    bool inb = ((unsigned)xi < (unsigned)D) && ((unsigned)yi < (unsigned)D) && ((unsigned)zi < (unsigned)D);
    int xc = min(max(xi, 0), D-1), yc = min(max(yi, 0), D-1), zc = min(max(zi, 0), D-1);
    int k = dz*4 + dy*2 + dx;
    voff[k] = (zc * D + yc) * D + xc;
    float ww = (dx ? fx : 1.f-fx) * (dy ? fy : 1.f-fy) * (dz ? fz : 1.f-fz);
    w[k] = inb ? ww : 0.f;
  }
}

template<int C, bool CL>
__device__ inline void apply_level(const float* __restrict__ vol, int b, int S,
                                   const int* voff, const float* w,
                                   float* __restrict__ outp) {
  if constexpr (CL) {
    long base[8];
    #pragma unroll
    for (int k = 0; k < 8; k++) base[k] = ((long)b * S + voff[k]) * C;
    #pragma unroll
    for (int ch = 0; ch < C; ch += 32) {
      float4 acc[8];
      #pragma unroll
      for (int j = 0; j < 8; j++) acc[j] = make_float4(0.f, 0.f, 0.f, 0.f);
      #pragma unroll
      for (int k = 0; k < 8; k++) {
        const float4* p = reinterpret_cast<const float4*>(vol + base[k] + ch);
        float wk = w[k];
        #pragma unroll
        for (int j = 0; j < 8; j++) {
          float4 v = p[j];
          acc[j].x += wk * v.x; acc[j].y += wk * v.y;
          acc[j].z += wk * v.z; acc[j].w += wk * v.w;
        }
      }
      #pragma unroll
      for (int j = 0; j < 8; j++) {
        outp[ch + j*4 + 0] = acc[j].x; outp[ch + j*4 + 1] = acc[j].y;
        outp[ch + j*4 + 2] = acc[j].z; outp[ch + j*4 + 3] = acc[j].w;
      }
    }
  } else {
    long bbase = (long)b * C * S;
    for (int c = 0; c < C; c++) {
      float s = 0.f;
      #pragma unroll
      for (int k = 0; k < 8; k++) s += w[k] * vol[bbase + (long)c * S + voff[k]];
      outp[c] = s;
    }
  }
}

template<bool CL>
__global__ __launch_bounds__(256) void sample_kernel(
    const float* __restrict__ coarse, const float* __restrict__ medium,
    const float* __restrict__ fine, const float* __restrict__ sdf,
    const float* __restrict__ M, const int* __restrict__ vidx,
    float* __restrict__ out, int N) {
  int n = blockIdx.x * blockDim.x + threadIdx.x;
  if (n >= N) return;
  int4 vi = reinterpret_cast<const int4*>(vidx)[n];
  int b = vi.x;
  float wx = vi.y * VOXEL, wy = vi.z * VOXEL, wz = vi.w * VOXEL;
  const float* m = M + b*12;
  float hx = m[0]*wx + m[1]*wy + m[2]*wz  + m[3];
  float hy = m[4]*wx + m[5]*wy + m[6]*wz  + m[7];
  float hz = m[8]*wx + m[9]*wy + m[10]*wz + m[11];
  float* outp = out + (long)n * 225;

  int off[8]; float w[8];
  make_corners(24, 4.f,  hx, hy, hz, off, w);
  apply_level<128, CL>(coarse, b, 24*24*24, off, w, outp);
  make_corners(48, 8.f,  hx, hy, hz, off, w);
  apply_level<64, CL>(medium, b, 48*48*48, off, w, outp + 128);
  make_corners(96, 16.f, hx, hy, hz, off, w);
  apply_level<32, CL>(fine,   b, 96*96*96, off, w, outp + 192);
  // sdf: same resolution & dims as fine -> reuse corners; C=1 layout is identical either way
  float s = 0.f;
  #pragma unroll
  for (int k = 0; k < 8; k++) s += w[k] * sdf[(long)b * 884736 + off[k]];
  outp[224] = s;
}

extern "C" void kernel_launch(void* const* d_in, const int* in_sizes, int n_in,
                              void* d_out, int out_size, void* d_ws, size_t ws_size,
                              hipStream_t stream) {
  const float* coarse = (const float*)d_in[0];
  const float* medium = (const float*)d_in[1];
  const float* fine   = (const float*)d_in[2];
  const float* sdf    = (const float*)d_in[3];
  const float* hist   = (const float*)d_in[4];
  const float* cur    = (const float*)d_in[5];
  const int*   vidx   = (const int*)d_in[6];
  float* out = (float*)d_out;

  int B = in_sizes[4] / 16;
  int N = in_sizes[6] / 4;

  const int Vc = 24*24*24, Vm = 48*48*48, Vf = 96*96*96;
  size_t fineB = (size_t)B * Vf * 32 * 4;
  size_t medB  = (size_t)B * Vm * 64 * 4;
  size_t coarB = (size_t)B * Vc * 128 * 4;
  size_t poseB = 256;
  size_t need = fineB + medB + coarB + poseB;

  bool fast = (ws_size >= need);
  float* fine_t = (float*)d_ws;
  float* med_t  = fine_t + (size_t)B * Vf * 32;
  float* coar_t = med_t  + (size_t)B * Vm * 64;
  float* M      = fast ? (coar_t + (size_t)B * Vc * 128) : (float*)d_ws;

  pose_kernel<<<1, B, 0, stream>>>(hist, cur, M, B);

  int blocks = (N + 255) / 256;
  if (fast) {
    transpose_kernel<128><<<dim3(Vc/64, B), 256, 0, stream>>>(coarse, coar_t, Vc);
    transpose_kernel<64> <<<dim3(Vm/64, B), 256, 0, stream>>>(medium, med_t,  Vm);
    transpose_kernel<32> <<<dim3(Vf/64, B), 256, 0, stream>>>(fine,   fine_t, Vf);
    sample_kernel<true><<<blocks, 256, 0, stream>>>(coar_t, med_t, fine_t, sdf, M, vidx, out, N);
  } else {
    sample_kernel<false><<<blocks, 256, 0, stream>>>(coarse, medium, fine, sdf, M, vidx, out, N);
  }
}

// Round 3
// 598.030 us; speedup vs baseline: 1.3604x; 1.3604x over previous
//
#include <hip/hip_runtime.h>

#define VOXEL 0.0625f

// ---------------- pose kernel ----------------
__device__ void inv4(const float* a_in, float* out) {
  float a[4][8];
  for (int i = 0; i < 4; i++) {
    for (int j = 0; j < 4; j++) { a[i][j] = a_in[i*4+j]; a[i][j+4] = (i==j) ? 1.f : 0.f; }
  }
  for (int col = 0; col < 4; col++) {
    int piv = col; float mx = fabsf(a[col][col]);
    for (int r = col+1; r < 4; r++) { float v = fabsf(a[r][col]); if (v > mx) { mx = v; piv = r; } }
    if (piv != col) for (int j = 0; j < 8; j++) { float t = a[col][j]; a[col][j] = a[piv][j]; a[piv][j] = t; }
    float d = 1.f / a[col][col];
    for (int j = 0; j < 8; j++) a[col][j] *= d;
    for (int r = 0; r < 4; r++) if (r != col) {
      float f = a[r][col];
      for (int j = 0; j < 8; j++) a[r][j] -= f * a[col][j];
    }
  }
  for (int i = 0; i < 4; i++) for (int j = 0; j < 4; j++) out[i*4+j] = a[i][j+4];
}

__global__ void pose_kernel(const float* __restrict__ hist, const float* __restrict__ cur,
                            float* __restrict__ M, int B) {
  int b = threadIdx.x;
  if (b >= B) return;
  float Hinv[16], T[16], Tinv[16];
  inv4(hist + b*16, Hinv);
  for (int i = 0; i < 4; i++) for (int j = 0; j < 4; j++) {
    float s = 0.f;
    for (int k = 0; k < 4; k++) s += cur[b*16 + i*4 + k] * Hinv[k*4 + j];
    T[i*4+j] = s;
  }
  inv4(T, Tinv);
  for (int i = 0; i < 3; i++) for (int j = 0; j < 4; j++) M[b*12 + i*4 + j] = Tinv[i*4+j];
}

// ---------------- transpose [B,C,V] -> [B,V,C], float4 both sides ----------------
template<int C, int VT>
__global__ __launch_bounds__(256) void transpose_kernel(const float* __restrict__ src,
                                                        float* __restrict__ dst, long V) {
  constexpr int LD = C + 1;     // +1 pad: phase-1 scalar writes conflict-free (2-way max)
  constexpr int VQ = VT / 4;
  constexpr int CQ = C / 4;
  __shared__ float lds[VT * LD];
  int b = blockIdx.y;
  long v0 = (long)blockIdx.x * VT;
  const float* s = src + (long)b * C * V + v0;
  float* d = dst + ((long)b * V + v0) * C;
  int tid = threadIdx.x;
  #pragma unroll
  for (int it = 0; it < (C * VQ) / 256; ++it) {     // 8 iters for all configs (C*VT == 8192)
    int idx = it * 256 + tid;
    int c = idx / VQ, vq = idx - c * VQ;
    float4 val = *reinterpret_cast<const float4*>(s + (long)c * V + 4 * vq);
    lds[(4*vq+0)*LD + c] = val.x;
    lds[(4*vq+1)*LD + c] = val.y;
    lds[(4*vq+2)*LD + c] = val.z;
    lds[(4*vq+3)*LD + c] = val.w;
  }
  __syncthreads();
  #pragma unroll
  for (int it = 0; it < (VT * CQ) / 256; ++it) {
    int idx = it * 256 + tid;
    int v = idx / CQ, cq = idx - v * CQ;
    float4 val;
    val.x = lds[v*LD + 4*cq + 0];
    val.y = lds[v*LD + 4*cq + 1];
    val.z = lds[v*LD + 4*cq + 2];
    val.w = lds[v*LD + 4*cq + 3];
    *reinterpret_cast<float4*>(d + (long)v * C + 4*cq) = val;
  }
}

// ---------------- corner math ----------------
__device__ inline void make_corners(int D, float res_inv,
                                    float hx, float hy, float hz,
                                    int* voff, float* w) {
  float Dm1 = (float)(D - 1);
  float v0 = hx * res_inv, v1 = hy * res_inv, v2 = hz * res_inv;
  float gx = fminf(fmaxf(v0 / Dm1 * 2.f - 1.f, -1.f), 1.f);
  float gy = fminf(fmaxf(v1 / Dm1 * 2.f - 1.f, -1.f), 1.f);
  float gz = fminf(fmaxf(v2 / Dm1 * 2.f - 1.f, -1.f), 1.f);
  float ix = ((gx + 1.f) * D - 1.f) * 0.5f;
  float iy = ((gy + 1.f) * D - 1.f) * 0.5f;
  float iz = ((gz + 1.f) * D - 1.f) * 0.5f;
  float fix = floorf(ix), fiy = floorf(iy), fiz = floorf(iz);
  int ix0 = (int)fix, iy0 = (int)fiy, iz0 = (int)fiz;
  float fx = ix - fix, fy = iy - fiy, fz = iz - fiz;
  #pragma unroll
  for (int dz = 0; dz < 2; dz++)
  #pragma unroll
  for (int dy = 0; dy < 2; dy++)
  #pragma unroll
  for (int dx = 0; dx < 2; dx++) {
    int xi = ix0 + dx, yi = iy0 + dy, zi = iz0 + dz;
    bool inb = ((unsigned)xi < (unsigned)D) && ((unsigned)yi < (unsigned)D) && ((unsigned)zi < (unsigned)D);
    int xc = min(max(xi, 0), D-1), yc = min(max(yi, 0), D-1), zc = min(max(zi, 0), D-1);
    int k = dz*4 + dy*2 + dx;
    voff[k] = (zc * D + yc) * D + xc;
    float ww = (dx ? fx : 1.f-fx) * (dy ? fy : 1.f-fy) * (dz ? fz : 1.f-fz);
    w[k] = inb ? ww : 0.f;
  }
}

// ---------------- fast sampler: one half-wave (32 lanes) per point ----------------
__global__ __launch_bounds__(256) void sample_fast_kernel(
    const float* __restrict__ coar_t, const float* __restrict__ med_t,
    const float* __restrict__ fine_t, const float* __restrict__ sdf,
    const float* __restrict__ M, const int* __restrict__ vidx,
    float* __restrict__ out, int N) {
  int tid = threadIdx.x;
  int hl = tid & 31;                       // lane within half-wave
  int n = blockIdx.x * 8 + (tid >> 5);     // 8 half-waves (points) per 256-thread block
  if (n >= N) return;
  int4 vi = reinterpret_cast<const int4*>(vidx)[n];
  int b = vi.x;
  float wx = vi.y * VOXEL, wy = vi.z * VOXEL, wz = vi.w * VOXEL;
  const float* m = M + b * 12;
  float hx = m[0]*wx + m[1]*wy + m[2]*wz  + m[3];
  float hy = m[4]*wx + m[5]*wy + m[6]*wz  + m[7];
  float hz = m[8]*wx + m[9]*wy + m[10]*wz + m[11];
  float* outp = out + (long)n * 225;

  int off[8]; float w[8];

  // coarse: C=128, lane -> channels [4hl, 4hl+3]
  make_corners(24, 4.f, hx, hy, hz, off, w);
  {
    const float* cb = coar_t + (long)b * (13824L * 128) + 4 * hl;
    float ax = 0.f, ay = 0.f, az = 0.f, aw = 0.f;
    #pragma unroll
    for (int k = 0; k < 8; k++) {
      float4 v = *reinterpret_cast<const float4*>(cb + (long)off[k] * 128);
      ax += w[k]*v.x; ay += w[k]*v.y; az += w[k]*v.z; aw += w[k]*v.w;
    }
    // out row is 225-strided -> not 16B aligned; scalar stores (L2 merges lines)
    outp[4*hl+0] = ax; outp[4*hl+1] = ay; outp[4*hl+2] = az; outp[4*hl+3] = aw;
  }

  // medium: C=64, lane -> channels [2hl, 2hl+1]
  make_corners(48, 8.f, hx, hy, hz, off, w);
  {
    const float* mb = med_t + (long)b * (110592L * 64) + 2 * hl;
    float ax = 0.f, ay = 0.f;
    #pragma unroll
    for (int k = 0; k < 8; k++) {
      float2 v = *reinterpret_cast<const float2*>(mb + (long)off[k] * 64);
      ax += w[k]*v.x; ay += w[k]*v.y;
    }
    outp[128 + 2*hl] = ax; outp[128 + 2*hl + 1] = ay;
  }

  // fine: C=32, lane -> channel hl; sdf reuses the same corners (same dims/res)
  make_corners(96, 16.f, hx, hy, hz, off, w);
  {
    const float* fb = fine_t + (long)b * (884736L * 32) + hl;
    float a = 0.f;
    #pragma unroll
    for (int k = 0; k < 8; k++) a += w[k] * fb[(long)off[k] * 32];
    outp[192 + hl] = a;

    float s = 0.f;
    if (hl < 8) s = w[hl] * sdf[(long)b * 884736 + off[hl]];
    s += __shfl_xor(s, 1);
    s += __shfl_xor(s, 2);
    s += __shfl_xor(s, 4);
    if (hl == 0) outp[224] = s;
  }
}

// ---------------- fallback (ws too small): per-thread strided sampling ----------------
template<int C>
__device__ inline void apply_level_strided(const float* __restrict__ vol, int b, int S,
                                           const int* voff, const float* w,
                                           float* __restrict__ outp) {
  long bbase = (long)b * C * S;
  for (int c = 0; c < C; c++) {
    float s = 0.f;
    #pragma unroll
    for (int k = 0; k < 8; k++) s += w[k] * vol[bbase + (long)c * S + voff[k]];
    outp[c] = s;
  }
}

__global__ __launch_bounds__(256) void sample_slow_kernel(
    const float* __restrict__ coarse, const float* __restrict__ medium,
    const float* __restrict__ fine, const float* __restrict__ sdf,
    const float* __restrict__ M, const int* __restrict__ vidx,
    float* __restrict__ out, int N) {
  int n = blockIdx.x * blockDim.x + threadIdx.x;
  if (n >= N) return;
  int4 vi = reinterpret_cast<const int4*>(vidx)[n];
  int b = vi.x;
  float wx = vi.y * VOXEL, wy = vi.z * VOXEL, wz = vi.w * VOXEL;
  const float* m = M + b*12;
  float hx = m[0]*wx + m[1]*wy + m[2]*wz  + m[3];
  float hy = m[4]*wx + m[5]*wy + m[6]*wz  + m[7];
  float hz = m[8]*wx + m[9]*wy + m[10]*wz + m[11];
  float* outp = out + (long)n * 225;
  int off[8]; float w[8];
  make_corners(24, 4.f,  hx, hy, hz, off, w);
  apply_level_strided<128>(coarse, b, 24*24*24, off, w, outp);
  make_corners(48, 8.f,  hx, hy, hz, off, w);
  apply_level_strided<64>(medium, b, 48*48*48, off, w, outp + 128);
  make_corners(96, 16.f, hx, hy, hz, off, w);
  apply_level_strided<32>(fine,   b, 96*96*96, off, w, outp + 192);
  float s = 0.f;
  #pragma unroll
  for (int k = 0; k < 8; k++) s += w[k] * sdf[(long)b * 884736 + off[k]];
  outp[224] = s;
}

extern "C" void kernel_launch(void* const* d_in, const int* in_sizes, int n_in,
                              void* d_out, int out_size, void* d_ws, size_t ws_size,
                              hipStream_t stream) {
  const float* coarse = (const float*)d_in[0];
  const float* medium = (const float*)d_in[1];
  const float* fine   = (const float*)d_in[2];
  const float* sdf    = (const float*)d_in[3];
  const float* hist   = (const float*)d_in[4];
  const float* cur    = (const float*)d_in[5];
  const int*   vidx   = (const int*)d_in[6];
  float* out = (float*)d_out;

  int B = in_sizes[4] / 16;
  int N = in_sizes[6] / 4;

  const long Vc = 24*24*24, Vm = 48*48*48, Vf = 96*96*96;
  size_t fineB = (size_t)B * Vf * 32 * 4;
  size_t medB  = (size_t)B * Vm * 64 * 4;
  size_t coarB = (size_t)B * Vc * 128 * 4;
  size_t need = fineB + medB + coarB + 256;

  bool fast = (ws_size >= need);
  float* fine_t = (float*)d_ws;
  float* med_t  = fine_t + (size_t)B * Vf * 32;
  float* coar_t = med_t  + (size_t)B * Vm * 64;
  float* M      = fast ? (coar_t + (size_t)B * Vc * 128) : (float*)d_ws;

  pose_kernel<<<1, B, 0, stream>>>(hist, cur, M, B);

  if (fast) {
    transpose_kernel<128, 64><<<dim3(Vc/64,  B), 256, 0, stream>>>(coarse, coar_t, Vc);
    transpose_kernel<64, 128><<<dim3(Vm/128, B), 256, 0, stream>>>(medium, med_t,  Vm);
    transpose_kernel<32, 256><<<dim3(Vf/256, B), 256, 0, stream>>>(fine,   fine_t, Vf);
    int blocks = (N + 7) / 8;   // 8 points per 256-thread block (half-wave per point)
    sample_fast_kernel<<<blocks, 256, 0, stream>>>(coar_t, med_t, fine_t, sdf, M, vidx, out, N);
  } else {
    int blocks = (N + 255) / 256;
    sample_slow_kernel<<<blocks, 256, 0, stream>>>(coarse, medium, fine, sdf, M, vidx, out, N);
  }
}